// Round 6
// baseline (99.221 us; speedup 1.0000x reference)
//
#include <hip/hip_runtime.h>

// VectorQuantizer: split-precision bf16 MFMA (16x16x32), 4-wave blocks,
// LDS-shared frag-linear codebook chunks, counted-vmcnt double buffer.
// z [65536,192] f32, codebook [512,192] f32
// out: z_q [65536*192] f32 ++ indices [65536] (as float)

#define NROWS 65536
#define D     192
#define V     512
#define MARGIN 5e-4f
#define NCHUNK 32                 // V / 16 entries per chunk
#define CHUNK_BYTES 12288         // 16 cols * 192 k * 2B * 2 planes

typedef __attribute__((ext_vector_type(8))) short short8;  // 8 bf16
typedef __attribute__((ext_vector_type(4))) float f32x4;   // 16x16 C frag

__device__ __forceinline__ unsigned short f2bf(float x) {   // RNE f32->bf16
    unsigned u = __float_as_uint(x);
    u += 0x7FFFu + ((u >> 16) & 1u);
    return (unsigned short)(u >> 16);
}
__device__ __forceinline__ float bf2f(unsigned short h) {
    return __uint_as_float(((unsigned)h) << 16);
}

// ---- prepass: codebook -> frag-linear bf16 hi/lo F + esq ----
// frag f = (c*6 + s)*2 + p ; F[f*64 + lane] = 8 bf16 of
//   col = c*16 + (lane&15), k = s*32 + (lane>>4)*8 + j
__global__ void vq_prep(const float* __restrict__ cb,
                        short8* __restrict__ F,
                        float* __restrict__ esq) {
    int u = blockIdx.x * 256 + threadIdx.x;       // 0..24575
    int lane = u & 63;
    int f = u >> 6;                                // 0..383
    int p = f & 1;
    int t = f >> 1;                                // c*6+s
    int c = t / 6, s = t - c * 6;
    int col  = c * 16 + (lane & 15);
    int koff = s * 32 + (lane >> 4) * 8;
    const float* src = cb + (size_t)col * D + koff;
    float4 a = *(const float4*)(src);
    float4 b = *(const float4*)(src + 4);
    float xs[8] = {a.x, a.y, a.z, a.w, b.x, b.y, b.z, b.w};
    short8 o;
    if (p == 0) {
#pragma unroll
        for (int j = 0; j < 8; ++j) o[j] = (short)f2bf(xs[j]);
    } else {
#pragma unroll
        for (int j = 0; j < 8; ++j) {
            unsigned short hb = f2bf(xs[j]);
            o[j] = (short)f2bf(xs[j] - bf2f(hb));
        }
    }
    F[u] = o;

    if (u < V) {                                   // esq, same order as rescan
        const float4* pp = (const float4*)(cb + (size_t)u * D);
        float4 es = make_float4(0.f, 0.f, 0.f, 0.f);
#pragma unroll
        for (int k = 0; k < D / 4; ++k) {
            float4 e = pp[k];
            es.x = fmaf(e.x, e.x, es.x); es.y = fmaf(e.y, e.y, es.y);
            es.z = fmaf(e.z, e.z, es.z); es.w = fmaf(e.w, e.w, es.w);
        }
        esq[u] = (es.x + es.y) + (es.z + es.w);
    }
}

// ---- exact fp32 rescan (round-1-verified bit-exact formula) ----
__device__ __noinline__ int vq_rescan(const float* __restrict__ z,
                                      const float* __restrict__ cb,
                                      const float* __restrict__ esq,
                                      int row, int lane) {
    const float4* zp = (const float4*)(z + (size_t)row * D);
    float4 s = make_float4(0.f, 0.f, 0.f, 0.f);
    for (int k = 0; k < D / 4; ++k) {
        float4 a = zp[k];
        s.x = fmaf(a.x, a.x, s.x); s.y = fmaf(a.y, a.y, s.y);
        s.z = fmaf(a.z, a.z, s.z); s.w = fmaf(a.w, a.w, s.w);
    }
    float zsq = (s.x + s.y) + (s.z + s.w);
    float bd = 3.402823466e+38f; int bi = V;
    for (int it = 0; it < V / 64; ++it) {
        int e = lane + it * 64;
        const float4* ep = (const float4*)(cb + (size_t)e * D);
        float4 a = make_float4(0.f, 0.f, 0.f, 0.f);
        for (int k = 0; k < D / 4; ++k) {
            float4 b = ep[k], zv = zp[k];
            a.x = fmaf(zv.x, b.x, a.x); a.y = fmaf(zv.y, b.y, a.y);
            a.z = fmaf(zv.z, b.z, a.z); a.w = fmaf(zv.w, b.w, a.w);
        }
        float dot = (a.x + a.y) + (a.z + a.w);
        float d = (zsq + esq[e]) - 2.f * dot;
        if (d < bd) { bd = d; bi = e; }
    }
    for (int m = 1; m < 64; m <<= 1) {
        float od = __shfl_xor(bd, m);
        int   oi = __shfl_xor(bi, m);
        if (od < bd || (od == bd && oi < bi)) { bd = od; bi = oi; }
    }
    return bi;
}

// ------------------------------ main kernel ------------------------------
__global__ __launch_bounds__(256, 4)
void vq_main(const float* __restrict__ z,
             const float* __restrict__ cb,
             const char* __restrict__ F,
             const float* __restrict__ esq,
             float* __restrict__ zq,
             float* __restrict__ idx_out) {
    __shared__ __align__(16) char lds_buf[2][CHUNK_BYTES];
    __shared__ float lds_esq[V];

    const int tid  = threadIdx.x;
    const int wave = tid >> 6;
    const int lane = tid & 63;
    const int n15  = lane & 15;
    const int g    = lane >> 4;

    const int rowblk = blockIdx.x * 64;
    const int wrow   = rowblk + wave * 16;
    const int myrow  = wrow + n15;                // A row this lane loads

    // esq -> LDS (waves 0,1)
    if (tid < 128)
        ((float4*)lds_esq)[tid] = ((const float4*)esq)[tid];

    // ---- A prologue: z row -> 6 k-step hi/lo frags ----
    short8 zhi[6], zlo[6];
    {
        const float* zr = z + (size_t)myrow * D + g * 8;
#pragma unroll
        for (int s = 0; s < 6; ++s) {
            float4 a = *(const float4*)(zr + s * 32);
            float4 b = *(const float4*)(zr + s * 32 + 4);
            float xs[8] = {a.x, a.y, a.z, a.w, b.x, b.y, b.z, b.w};
            short8 h, l;
#pragma unroll
            for (int j = 0; j < 8; ++j) {
                unsigned short hb = f2bf(xs[j]);
                h[j] = (short)hb;
                l[j] = (short)f2bf(xs[j] - bf2f(hb));
            }
            zhi[s] = h; zlo[s] = l;
        }
    }

    float v1[4], v2[4]; int i1[4];
#pragma unroll
    for (int r = 0; r < 4; ++r) { v1[r] = 3.402823466e+38f; v2[r] = 3.402823466e+38f; i1[r] = 0; }

#define STAGE(CC, BUF)                                                          \
    {                                                                           \
        const char* gsrc = F + (size_t)(CC) * CHUNK_BYTES + wave * 1024 + lane * 16; \
        char* ldst = &lds_buf[BUF][0] + wave * 1024;                            \
        _Pragma("unroll")                                                       \
        for (int it = 0; it < 3; ++it)                                          \
            __builtin_amdgcn_global_load_lds(                                   \
                (const __attribute__((address_space(1))) void*)(gsrc + it * 4096), \
                (__attribute__((address_space(3))) void*)(ldst + it * 4096),    \
                16, 0, 0);                                                      \
    }

    STAGE(0, 0);
    asm volatile("s_waitcnt lgkmcnt(0)" ::: "memory");   // esq ds_write drained

    for (int c = 0; c < NCHUNK; ++c) {
        const int cur = c & 1;
        if (c + 1 < NCHUNK) {
            STAGE(c + 1, cur ^ 1);                       // prefetch next chunk
            asm volatile("s_waitcnt vmcnt(3)" ::: "memory");  // chunk c staged
        } else {
            asm volatile("s_waitcnt vmcnt(0)" ::: "memory");
        }
        __builtin_amdgcn_s_barrier();                    // A: buf[cur] ready

        const char* B = &lds_buf[cur][0];
        f32x4 cA = {0.f, 0.f, 0.f, 0.f};
        f32x4 cB = {0.f, 0.f, 0.f, 0.f};
        f32x4 cC = {0.f, 0.f, 0.f, 0.f};
#pragma unroll
        for (int s = 0; s < 6; ++s) {
            short8 bh = *(const short8*)(B + (s * 2 + 0) * 1024 + lane * 16);
            short8 bl = *(const short8*)(B + (s * 2 + 1) * 1024 + lane * 16);
            cA = __builtin_amdgcn_mfma_f32_16x16x32_bf16(zhi[s], bh, cA, 0, 0, 0);
            cB = __builtin_amdgcn_mfma_f32_16x16x32_bf16(zlo[s], bh, cB, 0, 0, 0);
            cC = __builtin_amdgcn_mfma_f32_16x16x32_bf16(zhi[s], bl, cC, 0, 0, 0);
        }

        const float e = lds_esq[c * 16 + n15];
        const int idx = c * 16 + n15;
#pragma unroll
        for (int r = 0; r < 4; ++r) {
            float dot = (cA[r] + cB[r]) + cC[r];
            float d = fmaf(-2.f, dot, e);
            bool b = d < v1[r];
            v2[r] = fminf(b ? v1[r] : d, v2[r]);
            i1[r] = b ? idx : i1[r];
            v1[r] = b ? d : v1[r];
        }

        asm volatile("s_waitcnt lgkmcnt(0)" ::: "memory");
        __builtin_amdgcn_s_barrier();                    // B: reads of buf[cur] done
    }
#undef STAGE

    // ---- top2 merge across the 16 lanes of each group (masks 1,2,4,8) ----
#pragma unroll
    for (int r = 0; r < 4; ++r) {
#pragma unroll
        for (int m = 1; m <= 8; m <<= 1) {
            float ov1 = __shfl_xor(v1[r], m);
            int   oi1 = __shfl_xor(i1[r], m);
            float ov2 = __shfl_xor(v2[r], m);
            bool take = (ov1 < v1[r]) || ((ov1 == v1[r]) && (oi1 < i1[r]));
            float lose = take ? v1[r] : ov1;
            v2[r] = fminf(fminf(v2[r], ov2), lose);
            v1[r] = take ? ov1 : v1[r];
            i1[r] = take ? oi1 : i1[r];
        }
    }

    // ---- epilogue: rare exact rescan + gather + idx ----
#pragma unroll
    for (int r = 0; r < 4; ++r) {
        bool need = (v2[r] - v1[r]) <= MARGIN;
        unsigned long long bm = __ballot(need);
        int idx = i1[r];
        if (bm) {                                        // uniform, rare
            for (int gg = 0; gg < 4; ++gg) {
                if ((bm >> (gg * 16)) & 1ull) {
                    int ridx = vq_rescan(z, cb, esq, wrow + gg * 4 + r, lane);
                    if (g == gg) idx = ridx;
                }
            }
        }
        const int row = wrow + g * 4 + r;
        const float4* srcv = (const float4*)(cb + (size_t)idx * D);
        float4* dstv = (float4*)(zq + (size_t)row * D);
        dstv[n15]      = srcv[n15];
        dstv[n15 + 16] = srcv[n15 + 16];
        dstv[n15 + 32] = srcv[n15 + 32];
        if (n15 == 0) idx_out[row] = (float)idx;
    }
}

// --------- round-1 fallback (only if ws is unexpectedly small) ---------
#define TV 32
#define FBLOCK 128
__global__ __launch_bounds__(FBLOCK, 2)
void vq_argmin_fallback(const float* __restrict__ z, const float* __restrict__ cb,
                        float* __restrict__ zq, float* __restrict__ idx_out) {
    __shared__ float lds_cb[TV * D];
    __shared__ float lds_esq2[TV];
    const int row = blockIdx.x * FBLOCK + threadIdx.x;
    float4 zr[D / 4];
    const float4* zp = (const float4*)(z + (size_t)row * D);
    float4 s = make_float4(0.f, 0.f, 0.f, 0.f);
#pragma unroll
    for (int i = 0; i < D / 4; ++i) {
        zr[i] = zp[i];
        s.x = fmaf(zr[i].x, zr[i].x, s.x); s.y = fmaf(zr[i].y, zr[i].y, s.y);
        s.z = fmaf(zr[i].z, zr[i].z, s.z); s.w = fmaf(zr[i].w, zr[i].w, s.w);
    }
    const float zsq = (s.x + s.y) + (s.z + s.w);
    float best = 3.4e38f; int bidx = 0;
    for (int vt = 0; vt < V / TV; ++vt) {
        __syncthreads();
        const float4* cbp = (const float4*)(cb + (size_t)vt * TV * D);
        float4* l4 = (float4*)lds_cb;
#pragma unroll
        for (int i = 0; i < (TV * D / 4) / FBLOCK; ++i)
            l4[threadIdx.x + i * FBLOCK] = cbp[threadIdx.x + i * FBLOCK];
        __syncthreads();
        if (threadIdx.x < TV) {
            const float* e = lds_cb + threadIdx.x * D;
            float4 es = make_float4(0.f, 0.f, 0.f, 0.f);
#pragma unroll
            for (int k = 0; k < D; k += 4) {
                es.x = fmaf(e[k], e[k], es.x); es.y = fmaf(e[k+1], e[k+1], es.y);
                es.z = fmaf(e[k+2], e[k+2], es.z); es.w = fmaf(e[k+3], e[k+3], es.w);
            }
            lds_esq2[threadIdx.x] = (es.x + es.y) + (es.z + es.w);
        }
        __syncthreads();
#pragma unroll 2
        for (int v = 0; v < TV; ++v) {
            const float4* e4 = (const float4*)(lds_cb + v * D);
            float4 a = make_float4(0.f, 0.f, 0.f, 0.f);
#pragma unroll
            for (int k = 0; k < D / 4; ++k) {
                float4 b = e4[k];
                a.x = fmaf(zr[k].x, b.x, a.x); a.y = fmaf(zr[k].y, b.y, a.y);
                a.z = fmaf(zr[k].z, b.z, a.z); a.w = fmaf(zr[k].w, b.w, a.w);
            }
            const float dot = (a.x + a.y) + (a.z + a.w);
            const float dist = (zsq + lds_esq2[v]) - 2.f * dot;
            if (dist < best) { best = dist; bidx = vt * TV + v; }
        }
    }
    float4* zqp = (float4*)(zq + (size_t)row * D);
    const float4* bp = (const float4*)(cb + (size_t)bidx * D);
#pragma unroll
    for (int i = 0; i < D / 4; ++i) zqp[i] = bp[i];
    idx_out[row] = (float)bidx;
}

extern "C" void kernel_launch(void* const* d_in, const int* in_sizes, int n_in,
                              void* d_out, int out_size, void* d_ws, size_t ws_size,
                              hipStream_t stream) {
    const float* z  = (const float*)d_in[0];
    const float* cb = (const float*)d_in[1];
    float* zq      = (float*)d_out;
    float* idx_out = (float*)d_out + (size_t)NROWS * D;

    const size_t f_bytes = (size_t)384 * 1024;              // 384 frags x 1KB
    const size_t need = f_bytes + V * sizeof(float);
    if (ws_size < need) {
        vq_argmin_fallback<<<NROWS / FBLOCK, FBLOCK, 0, stream>>>(z, cb, zq, idx_out);
        return;
    }
    short8* F  = (short8*)d_ws;
    float* esq = (float*)((char*)d_ws + f_bytes);

    vq_prep<<<96, 256, 0, stream>>>(cb, F, esq);
    vq_main<<<NROWS / 64, 256, 0, stream>>>(z, cb, (const char*)F, esq, zq, idx_out);
}